// Round 4
// baseline (316.627 us; speedup 1.0000x reference)
//
#include <hip/hip_runtime.h>

// SpatialTransformer: dense 2D bilinear warp with edge clamping.
// img: [B,C,H,W] fp32, trf: [B,2,H,W] fp32 (ij displacements), out: [B,C,H,W] fp32.
// B=16, C=4, H=W=768.
//
// R5: R4 (fused LDS-staged warp) with TH 32->16. Staged tile 32x80 float4 =
// 40960 B LDS -> exactly 4 blocks/CU (163840 B), doubling resident blocks:
// R4's counters showed latency-bound stage->barrier->compute chains (occ 40%,
// VALU 19%, HBM 29%) with only 2 blocks/CU to overlap them. 100% wave cap now.
// Staging loop is exactly 5 iterations (2560 px / 512 thr), no guard.

typedef float fvec4 __attribute__((ext_vector_type(4)));

#define BB 16
#define CC 4
#define HH 768
#define WW 768
#define HWSZ (HH * WW)

#define TW 64
#define TH 16
#define HALO 8
#define TLW (TW + 2 * HALO)          // 80
#define TLH (TH + 2 * HALO)          // 32
#define TILE_PX (TLH * TLW)          // 2560 staged pixels = 40960 B as float4
#define NXT (WW / TW)                // 12
#define NYT (HH / TH)                // 48
#define TILES_PER_B (NXT * NYT)      // 576
#define NTILES (TILES_PER_B * BB)    // 9216
#define NXCD 8
#define NTHR 512                     // 8 waves; wave w owns rows 2w..2w+1
#define RPT 2                        // rows per thread
#define NSTG (TILE_PX / NTHR)        // 5 staging iterations, exact

__global__ __launch_bounds__(NTHR, 8) void st_warp_lds(
    const float* __restrict__ img,
    const float* __restrict__ trf,
    float* __restrict__ out)
{
    __shared__ fvec4 tile[TILE_PX];  // 40960 B -> 4 blocks/CU exactly

    // XCD-aware swizzle: block l -> XCD l%8; each XCD walks ht fastest down a
    // 64-wide column band so vertically-adjacent tiles' halos overlap in L2.
    int l = blockIdx.x;
    int xcd = l & (NXCD - 1);
    int t = xcd * (NTILES / NXCD) + (l >> 3);
    int b = t / TILES_PER_B;
    int rem = t - b * TILES_PER_B;
    int wt = rem / NYT;
    int ht = rem - wt * NYT;
    int h0 = ht * TH, w0 = wt * TW;
    int oy = h0 - HALO, ox = w0 - HALO;  // staged-tile origin (clamped at edges)

    const float* ib = img + (size_t)b * CC * HWSZ;
    const float* tb = trf + (size_t)b * 2 * HWSZ;
    float* ob = out + (size_t)b * CC * HWSZ;

    int tid = threadIdx.x;
    int lane = tid & 63;            // one wave = one 64-wide row: coalesced
    int wv = tid >> 6;              // 0..7
    int hbase = h0 + wv * RPT;
    int w = w0 + lane;

    // Issue trf loads FIRST: latency hides under the staging phase.
    float dys[RPT], dxs[RPT];
#pragma unroll
    for (int r = 0; r < RPT; ++r) {
        int p = (hbase + r) * WW + w;
        dys[r] = __builtin_nontemporal_load(tb + p);
        dxs[r] = __builtin_nontemporal_load(tb + p + HWSZ);
    }

    // Stage img tile+halo: planar -> interleaved float4, edge-clamped.
    // Lane-consecutive plane reads (coalesced); ds_write_b128 at 16B stride
    // (16-lane phase spans 256B = all 32 banks once: conflict-free).
#pragma unroll
    for (int i = 0; i < NSTG; ++i) {
        int s = tid + i * NTHR;
        int ly = s / TLW;
        int lx = s - ly * TLW;
        int gy = min(max(oy + ly, 0), HH - 1);
        int gx = min(max(ox + lx, 0), WW - 1);
        int gp = gy * WW + gx;
        fvec4 px = { ib[gp], ib[gp + HWSZ], ib[gp + 2 * HWSZ], ib[gp + 3 * HWSZ] };
        tile[s] = px;
    }
    __syncthreads();

    const float maxy = (float)(HH - 1);
    const float maxx = (float)(WW - 1);

#pragma unroll
    for (int r = 0; r < RPT; ++r) {
        int h = hbase + r;
        int p = h * WW + w;

        float y = (float)h + dys[r];
        float x = (float)w + dxs[r];

        float cy = fminf(fmaxf(y, 0.0f), maxy);
        float cx = fminf(fmaxf(x, 0.0f), maxx);

        float f0y = fminf(fmaxf(floorf(y), 0.0f), maxy);
        float f0x = fminf(fmaxf(floorf(x), 0.0f), maxx);
        float f1y = fminf(f0y + 1.0f, maxy);
        float f1x = fminf(f0x + 1.0f, maxx);

        // neurite convention: weight of floor corner = loc1 - clipped
        float wy0 = f1y - cy;
        float wx0 = f1x - cx;
        float wy1 = 1.0f - wy0;
        float wx1 = 1.0f - wx0;

        int i0y = (int)f0y;
        int i0x = (int)f0x;
        int i1y = (int)f1y;
        int i1x = (int)f1x;

        float w00 = wy0 * wx0;
        float w01 = wy0 * wx1;
        float w10 = wy1 * wx0;
        float w11 = wy1 * wx1;

        fvec4 v;
        if (i0y >= oy && i1y <= oy + TLH - 1 && i0x >= ox && i1x <= ox + TLW - 1) {
            // In staged tile (always true for |disp| <= HALO).
            int l0 = (i0y - oy) * TLW - ox;
            int l1 = (i1y - oy) * TLW - ox;
            fvec4 c00 = tile[l0 + i0x];
            fvec4 c01 = tile[l0 + i1x];
            fvec4 c10 = tile[l1 + i0x];
            fvec4 c11 = tile[l1 + i1x];
            v = w00 * c00 + w01 * c01 + w10 * c10 + w11 * c11;
        } else {
            // Rare (never on N(0,1) inputs): global planar gather fallback.
            int o00 = i0y * WW + i0x;
            int o01 = i0y * WW + i1x;
            int o10 = i1y * WW + i0x;
            int o11 = i1y * WW + i1x;
#pragma unroll
            for (int c = 0; c < CC; ++c) {
                const float* ic = ib + c * HWSZ;
                v[c] = w00 * ic[o00] + w01 * ic[o01]
                     + w10 * ic[o10] + w11 * ic[o11];
            }
        }

        // Planar stores: wave writes 256B/channel/row — full-line coalesced.
        __builtin_nontemporal_store(v.x, ob + 0 * HWSZ + p);
        __builtin_nontemporal_store(v.y, ob + 1 * HWSZ + p);
        __builtin_nontemporal_store(v.z, ob + 2 * HWSZ + p);
        __builtin_nontemporal_store(v.w, ob + 3 * HWSZ + p);
    }
}

extern "C" void kernel_launch(void* const* d_in, const int* in_sizes, int n_in,
                              void* d_out, int out_size, void* d_ws, size_t ws_size,
                              hipStream_t stream) {
    const float* img = (const float*)d_in[0];
    const float* trf = (const float*)d_in[1];
    float* out = (float*)d_out;

    st_warp_lds<<<NTILES, NTHR, 0, stream>>>(img, trf, out);
}